// Round 7
// baseline (184.590 us; speedup 1.0000x reference)
//
#include <hip/hip_runtime.h>
#include <hip/hip_bf16.h>

#define BB 4
#define NN 4096
#define DIN 512
#define DD 64

typedef __attribute__((ext_vector_type(8))) short short8;
typedef __attribute__((ext_vector_type(4))) float f32x4;
typedef __attribute__((ext_vector_type(4))) unsigned short us4;
using bf16 = __hip_bfloat16;

__device__ inline void mfma_16x16x32(f32x4& d, short8 a, short8 b) {
    asm("v_mfma_f32_16x16x32_bf16 %0, %1, %2, %0" : "+v"(d) : "v"(a), "v"(b));
}

__device__ inline short8 load_cvt8(const float* __restrict__ src) {
    f32x4 f0 = *(const f32x4*)(src);
    f32x4 f1 = *(const f32x4*)(src + 4);
    bf16 t[8];
    #pragma unroll
    for (int j = 0; j < 4; ++j) t[j]     = __float2bfloat16(f0[j]);
    #pragma unroll
    for (int j = 0; j < 4; ++j) t[4 + j] = __float2bfloat16(f1[j]);
    return *(short8*)t;
}

// prefix of work units: U(qt) = ceil(T(qt)/2^cl), T = (qt+2)>>1
// U(qt) = (qt + 2C) >> (cl+1), C = 1<<cl.  pfx(qt) = sum_{j<qt} U(j).
__host__ __device__ inline int pfx(int qt, int cl) {
    int K = 2 << cl;                 // 2C
    int n = qt + K;
    int a = n >> (cl + 1);
    int r = n - (a << (cl + 1));
    return a * (a - 1) * (K >> 1) + r * a;
}

// ---------------- W transpose+convert: WT[g][kk] = W_{g/64}[kk][g%64] -----
__global__ __launch_bounds__(256) void convw_kernel(
    const float* __restrict__ Wq, const float* __restrict__ Wk,
    const float* __restrict__ Wv, bf16* __restrict__ WT)
{
    int idx = blockIdx.x * 256 + threadIdx.x;   // 3*64*512 = 98304
    int w   = idx >> 15;
    int rem = idx & 32767;
    int n   = rem >> 9;
    int kk  = rem & 511;
    const float* W = (w == 0) ? Wq : (w == 1) ? Wk : Wv;
    WT[idx] = __float2bfloat16(W[kk * DD + n]);
}

// ---------------- MFMA projection: 16 rows/block, 1024 blocks -------------
__global__ __launch_bounds__(256) void proj_kernel(
    const float* __restrict__ x, const bf16* __restrict__ WT,
    bf16* __restrict__ q, bf16* __restrict__ k, bf16* __restrict__ vT)
{
    const int tid   = threadIdx.x;
    const int row0  = blockIdx.x * 16;
    const int b     = row0 >> 12;
    const int nrow0 = row0 & 4095;
    const int lane  = tid & 63;
    const int l16   = lane & 15;
    const int lg    = lane >> 4;
    const int wave  = tid >> 6;
    const int cbase = wave * 48;

    f32x4 acc[3];
    #pragma unroll
    for (int ct = 0; ct < 3; ++ct) acc[ct] = (f32x4){0.f, 0.f, 0.f, 0.f};

    const float* xa = x  + (size_t)(row0 + l16) * DIN + lg * 8;
    const bf16*  wb = WT + (size_t)(cbase + l16) * DIN + lg * 8;

    #pragma unroll 4
    for (int ks = 0; ks < 16; ++ks) {
        short8 a  = load_cvt8(xa + ks * 32);
        short8 w0 = *(const short8*)(wb + ks * 32);
        short8 w1 = *(const short8*)(wb + 16 * DIN + ks * 32);
        short8 w2 = *(const short8*)(wb + 32 * DIN + ks * 32);
        mfma_16x16x32(acc[0], a, w0);
        mfma_16x16x32(acc[1], a, w1);
        mfma_16x16x32(acc[2], a, w2);
    }

    #pragma unroll
    for (int ct = 0; ct < 3; ++ct) {
        int g = cbase + ct * 16 + l16;
        int w = g >> 6;
        int n = g & 63;
        if (w == 2) {
            us4 pv;
            #pragma unroll
            for (int r = 0; r < 4; ++r) {
                bf16 hv = __float2bfloat16(acc[ct][r]);
                pv[r] = *(unsigned short*)&hv;
            }
            *(us4*)(vT + ((size_t)b * DD + n) * NN + nrow0 + lg * 4) = pv;
        } else {
            bf16* dst = (w == 0) ? q : k;
            float sc  = (w == 0) ? 0.125f : 1.0f;
            #pragma unroll
            for (int r = 0; r < 4; ++r) {
                int row = nrow0 + lg * 4 + r;
                dst[((size_t)b * NN + row) * DD + n] =
                    __float2bfloat16(acc[ct][r] * sc);
            }
        }
    }
}

// ---------------- equal-work split-KV flash attention ---------------------
// block = one work unit: (b, qt, s) with exactly <= 2^cl 128-key tiles
__global__ __launch_bounds__(256, 4) void attn_split_kernel(
    const bf16* __restrict__ q, const bf16* __restrict__ k,
    const bf16* __restrict__ vT,
    float* __restrict__ partO, float* __restrict__ partML, int cl)
{
    const int perB = pfx(64, cl);
    const int wblk = blockIdx.x;
    const int b    = wblk / perB;
    const int u    = wblk - b * perB;
    int lo = 0, hi = 63;
    while (lo < hi) {
        int mid = (lo + hi + 1) >> 1;
        if (pfx(mid, cl) <= u) lo = mid; else hi = mid - 1;
    }
    const int qt = lo;
    const int s  = u - pfx(qt, cl);
    const size_t sidx = (size_t)wblk;        // canonical partial slot

    const int T  = (qt + 2) >> 1;            // # 128-key tiles for this qt
    const int t0 = s << cl;
    int t1 = t0 + (1 << cl); if (t1 > T) t1 = T;

    const int wave = threadIdx.x >> 6;
    const int lane = threadIdx.x & 63;
    const int l16  = lane & 15;
    const int lg   = lane >> 4;

    __shared__ __align__(16) bf16 p_lds[4][16][128];   // 16 KB, XOR-swizzled
    char* pbase_lds = (char*)p_lds + wave * 4096;

    const int row0g = qt * 64 + wave * 16;

    const bf16* qbase = q + ((size_t)b * NN + row0g + l16) * DD + lg * 8;
    short8 qfrag0 = *(const short8*)(qbase);
    short8 qfrag1 = *(const short8*)(qbase + 32);

    f32x4 oacc[4];
    #pragma unroll
    for (int dt = 0; dt < 4; ++dt) oacc[dt] = (f32x4){0.f, 0.f, 0.f, 0.f};
    float m[4], l[4];
    #pragma unroll
    for (int r = 0; r < 4; ++r) { m[r] = -INFINITY; l[r] = 0.f; }

    const bf16* kbase0 = k + ((size_t)b * NN + l16) * DD + lg * 8;
    const bf16* vbase0 = vT + ((size_t)b * DD + l16) * NN + lg * 8;

    #pragma unroll 1
    for (int t = t0; t < t1; ++t) {
        const bf16* kbase = kbase0 + (size_t)t * 128 * DD;
        f32x4 sc[8];
        #pragma unroll
        for (int ct = 0; ct < 8; ++ct) sc[ct] = (f32x4){0.f, 0.f, 0.f, 0.f};

        {   // K in two half-batches (32 VGPRs at a time)
            short8 kf[4][2];
            #pragma unroll
            for (int ct = 0; ct < 4; ++ct) {
                kf[ct][0] = *(const short8*)(kbase + (size_t)ct * 16 * DD);
                kf[ct][1] = *(const short8*)(kbase + (size_t)ct * 16 * DD + 32);
            }
            #pragma unroll
            for (int ct = 0; ct < 4; ++ct) {
                mfma_16x16x32(sc[ct], qfrag0, kf[ct][0]);
                mfma_16x16x32(sc[ct], qfrag1, kf[ct][1]);
            }
            #pragma unroll
            for (int ct = 0; ct < 4; ++ct) {
                kf[ct][0] = *(const short8*)(kbase + (size_t)(ct + 4) * 16 * DD);
                kf[ct][1] = *(const short8*)(kbase + (size_t)(ct + 4) * 16 * DD + 32);
            }
            #pragma unroll
            for (int ct = 0; ct < 4; ++ct) {
                mfma_16x16x32(sc[ct + 4], qfrag0, kf[ct][0]);
                mfma_16x16x32(sc[ct + 4], qfrag1, kf[ct][1]);
            }
        }

        // early-issue V half A (kc 0..1) — latency hides under softmax
        const bf16* vbase = vbase0 + (size_t)t * 128;
        short8 vfA[4][2];
        #pragma unroll
        for (int dt = 0; dt < 4; ++dt) {
            vfA[dt][0] = *(const short8*)(vbase + (size_t)dt * 16 * NN);
            vfA[dt][1] = *(const short8*)(vbase + (size_t)dt * 16 * NN + 32);
        }

        // causal mask (only when tile touches the diagonal)
        if (t * 128 + 127 > row0g) {
            #pragma unroll
            for (int ct = 0; ct < 8; ++ct) {
                int gk = t * 128 + ct * 16 + l16;
                #pragma unroll
                for (int r = 0; r < 4; ++r)
                    if (gk > row0g + lg * 4 + r)
                        sc[ct][r] = -INFINITY;
            }
        }

        // online softmax over 128 keys
        float mt[4];
        #pragma unroll
        for (int r = 0; r < 4; ++r) {
            float a = fmaxf(fmaxf(sc[0][r], sc[1][r]), fmaxf(sc[2][r], sc[3][r]));
            float c = fmaxf(fmaxf(sc[4][r], sc[5][r]), fmaxf(sc[6][r], sc[7][r]));
            mt[r] = fmaxf(a, c);
        }
        #pragma unroll
        for (int off = 1; off < 16; off <<= 1)
            #pragma unroll
            for (int r = 0; r < 4; ++r)
                mt[r] = fmaxf(mt[r], __shfl_xor(mt[r], off));

        float alpha[4];
        #pragma unroll
        for (int r = 0; r < 4; ++r) {
            float mn = fmaxf(m[r], mt[r]);
            alpha[r] = __expf(m[r] - mn);
            m[r] = mn;
        }

        float ls[4] = {0.f, 0.f, 0.f, 0.f};
        #pragma unroll
        for (int ct = 0; ct < 8; ++ct)
            #pragma unroll
            for (int r = 0; r < 4; ++r) {
                float p = __expf(sc[ct][r] - m[r]);
                sc[ct][r] = p;
                ls[r] += p;
            }
        #pragma unroll
        for (int off = 1; off < 16; off <<= 1)
            #pragma unroll
            for (int r = 0; r < 4; ++r)
                ls[r] += __shfl_xor(ls[r], off);
        #pragma unroll
        for (int r = 0; r < 4; ++r)
            l[r] = l[r] * alpha[r] + ls[r];

        #pragma unroll
        for (int dt = 0; dt < 4; ++dt)
            #pragma unroll
            for (int r = 0; r < 4; ++r)
                oacc[dt][r] *= alpha[r];

        // P -> LDS (XOR-swizzled rows)
        #pragma unroll
        for (int ct = 0; ct < 8; ++ct)
            #pragma unroll
            for (int r = 0; r < 4; ++r) {
                int row_w = lg * 4 + r;
                int boff  = row_w * 256 + ((((ct * 16 + l16) * 2)) ^ ((row_w & 7) << 4));
                *(bf16*)(pbase_lds + boff) = __float2bfloat16(sc[ct][r]);
            }
        asm volatile("s_waitcnt lgkmcnt(0)" ::: "memory");

        // V half B (kc 2..3)
        short8 vfB[4][2];
        #pragma unroll
        for (int dt = 0; dt < 4; ++dt) {
            vfB[dt][0] = *(const short8*)(vbase + (size_t)dt * 16 * NN + 64);
            vfB[dt][1] = *(const short8*)(vbase + (size_t)dt * 16 * NN + 96);
        }

        short8 pa[4];
        #pragma unroll
        for (int kc = 0; kc < 4; ++kc)
            pa[kc] = *(const short8*)(pbase_lds + l16 * 256 +
                                      ((kc * 64 + lg * 16) ^ ((l16 & 7) << 4)));

        #pragma unroll
        for (int dt = 0; dt < 4; ++dt) {
            mfma_16x16x32(oacc[dt], pa[0], vfA[dt][0]);
            mfma_16x16x32(oacc[dt], pa[1], vfA[dt][1]);
            mfma_16x16x32(oacc[dt], pa[2], vfB[dt][0]);
            mfma_16x16x32(oacc[dt], pa[3], vfB[dt][1]);
        }
    }

    // write partials (unnormalized)
    #pragma unroll
    for (int r = 0; r < 4; ++r) {
        int row = wave * 16 + lg * 4 + r;
        #pragma unroll
        for (int dt = 0; dt < 4; ++dt)
            partO[sidx * 4096 + row * 64 + dt * 16 + l16] = oacc[dt][r];
        if (l16 == 0) {
            partML[sidx * 128 + row]      = m[r];
            partML[sidx * 128 + 64 + row] = l[r];
        }
    }
}

// ---------------- combine partials: 4 blocks per (b,qt) -------------------
__global__ __launch_bounds__(256) void combine_kernel(
    const float* __restrict__ partO, const float* __restrict__ partML,
    float* __restrict__ out, int cl)
{
    const int blk4 = blockIdx.x;             // (b*64+qt)*4 + quarter
    const int blk  = blk4 >> 2;
    const int qt   = blk & 63;
    const int b    = blk >> 6;
    const int tid  = threadIdx.x;
    const int row  = (blk4 & 3) * 16 + (tid >> 4);
    const int c    = (tid & 15) << 2;

    const int perB = pfx(64, cl);
    const size_t base = (size_t)b * perB + pfx(qt, cl);
    const int K2 = 2 << cl;
    const int U  = (qt + K2) >> (cl + 1);    // # work units for this qt

    float M = -INFINITY;
    for (int s = 0; s < U; ++s)
        M = fmaxf(M, partML[(base + s) * 128 + row]);

    float L = 0.f;
    f32x4 acc = (f32x4){0.f, 0.f, 0.f, 0.f};
    for (int s = 0; s < U; ++s) {
        float e = __expf(partML[(base + s) * 128 + row] - M);
        L += partML[(base + s) * 128 + 64 + row] * e;
        acc += *(const f32x4*)(partO + (base + s) * 4096 + row * 64 + c) * e;
    }
    *(f32x4*)(out + (size_t)blk * 4096 + row * 64 + c) = acc * (1.f / L);
}

extern "C" void kernel_launch(void* const* d_in, const int* in_sizes, int n_in,
                              void* d_out, int out_size, void* d_ws, size_t ws_size,
                              hipStream_t stream) {
    const float* x  = (const float*)d_in[0];
    const float* Wq = (const float*)d_in[1];
    const float* Wk = (const float*)d_in[2];
    const float* Wv = (const float*)d_in[3];

    bf16* q  = (bf16*)d_ws;
    bf16* k  = q  + (size_t)BB * NN * DD;
    bf16* vT = k  + (size_t)BB * NN * DD;
    bf16* WT = vT + (size_t)BB * NN * DD;
    char* pbase = (char*)(WT + 3 * DD * DIN);
    size_t mis = (size_t)pbase & 15;
    if (mis) pbase += 16 - mis;
    size_t fixed = (size_t)(pbase - (char*)d_ws);

    int cl = 1, perB = 0;
    for (; cl <= 3; ++cl) {
        perB = pfx(64, cl);
        size_t need = fixed + (size_t)BB * perB * (4096 + 128) * sizeof(float);
        if (need <= ws_size) break;
    }
    if (cl > 3) { cl = 3; perB = pfx(64, cl); }

    float* partO  = (float*)pbase;
    float* partML = partO + (size_t)BB * perB * 4096;

    convw_kernel<<<(3 * DD * DIN) / 256, 256, 0, stream>>>(Wq, Wk, Wv, WT);
    proj_kernel<<<BB * NN / 16, 256, 0, stream>>>(x, WT, q, k, vT);
    attn_split_kernel<<<BB * perB, 256, 0, stream>>>(q, k, vT, partO, partML, cl);
    combine_kernel<<<BB * 64 * 4, 256, 0, stream>>>(partO, partML, (float*)d_out, cl);
}

// Round 8
// 128.612 us; speedup vs baseline: 1.4352x; 1.4352x over previous
//
#include <hip/hip_runtime.h>
#include <hip/hip_bf16.h>

#define BB 4
#define NN 4096
#define DIN 512
#define DD 64

typedef __attribute__((ext_vector_type(8))) short short8;
typedef __attribute__((ext_vector_type(4))) float f32x4;
typedef __attribute__((ext_vector_type(4))) unsigned short us4;
using bf16 = __hip_bfloat16;

__device__ inline void mfma_16x16x32(f32x4& d, short8 a, short8 b) {
    asm("v_mfma_f32_16x16x32_bf16 %0, %1, %2, %0" : "+v"(d) : "v"(a), "v"(b));
}

__device__ inline short8 load_cvt8(const float* __restrict__ src) {
    f32x4 f0 = *(const f32x4*)(src);
    f32x4 f1 = *(const f32x4*)(src + 4);
    bf16 t[8];
    #pragma unroll
    for (int j = 0; j < 4; ++j) t[j]     = __float2bfloat16(f0[j]);
    #pragma unroll
    for (int j = 0; j < 4; ++j) t[4 + j] = __float2bfloat16(f1[j]);
    return *(short8*)t;
}

// prefix of work units: U(qt) = ceil(T(qt)/2^cl), T = (qt+2)>>1
__host__ __device__ inline int pfx(int qt, int cl) {
    int K = 2 << cl;                 // 2C
    int n = qt + K;
    int a = n >> (cl + 1);
    int r = n - (a << (cl + 1));
    return a * (a - 1) * (K >> 1) + r * a;
}

// ---------------- W transpose+convert: WT[g][kk] = W_{g/64}[kk][g%64] -----
__global__ __launch_bounds__(256) void convw_kernel(
    const float* __restrict__ Wq, const float* __restrict__ Wk,
    const float* __restrict__ Wv, bf16* __restrict__ WT)
{
    int idx = blockIdx.x * 256 + threadIdx.x;   // 3*64*512 = 98304
    int w   = idx >> 15;
    int rem = idx & 32767;
    int n   = rem >> 9;
    int kk  = rem & 511;
    const float* W = (w == 0) ? Wq : (w == 1) ? Wk : Wv;
    WT[idx] = __float2bfloat16(W[kk * DD + n]);
}

// ---------------- MFMA projection: 16 rows/block, 1024 blocks -------------
__global__ __launch_bounds__(256) void proj_kernel(
    const float* __restrict__ x, const bf16* __restrict__ WT,
    bf16* __restrict__ q, bf16* __restrict__ k, bf16* __restrict__ vT)
{
    const int tid   = threadIdx.x;
    const int row0  = blockIdx.x * 16;
    const int b     = row0 >> 12;
    const int nrow0 = row0 & 4095;
    const int lane  = tid & 63;
    const int l16   = lane & 15;
    const int lg    = lane >> 4;
    const int wave  = tid >> 6;
    const int cbase = wave * 48;

    f32x4 acc[3];
    #pragma unroll
    for (int ct = 0; ct < 3; ++ct) acc[ct] = (f32x4){0.f, 0.f, 0.f, 0.f};

    const float* xa = x  + (size_t)(row0 + l16) * DIN + lg * 8;
    const bf16*  wb = WT + (size_t)(cbase + l16) * DIN + lg * 8;

    #pragma unroll 4
    for (int ks = 0; ks < 16; ++ks) {
        short8 a  = load_cvt8(xa + ks * 32);
        short8 w0 = *(const short8*)(wb + ks * 32);
        short8 w1 = *(const short8*)(wb + 16 * DIN + ks * 32);
        short8 w2 = *(const short8*)(wb + 32 * DIN + ks * 32);
        mfma_16x16x32(acc[0], a, w0);
        mfma_16x16x32(acc[1], a, w1);
        mfma_16x16x32(acc[2], a, w2);
    }

    #pragma unroll
    for (int ct = 0; ct < 3; ++ct) {
        int g = cbase + ct * 16 + l16;
        int w = g >> 6;
        int n = g & 63;
        if (w == 2) {
            us4 pv;
            #pragma unroll
            for (int r = 0; r < 4; ++r) {
                bf16 hv = __float2bfloat16(acc[ct][r]);
                pv[r] = *(unsigned short*)&hv;
            }
            *(us4*)(vT + ((size_t)b * DD + n) * NN + nrow0 + lg * 4) = pv;
        } else {
            bf16* dst = (w == 0) ? q : k;
            float sc  = (w == 0) ? 0.125f : 1.0f;
            #pragma unroll
            for (int r = 0; r < 4; ++r) {
                int row = nrow0 + lg * 4 + r;
                dst[((size_t)b * NN + row) * DD + n] =
                    __float2bfloat16(acc[ct][r] * sc);
            }
        }
    }
}

// ---------------- equal-work split-KV flash attention ---------------------
// block = one work unit: (b, qt, s) with exactly <= 2^cl 128-key tiles
__global__ __launch_bounds__(256) void attn_split_kernel(
    const bf16* __restrict__ q, const bf16* __restrict__ k,
    const bf16* __restrict__ vT,
    float* __restrict__ partO, float* __restrict__ partML, int cl)
{
    const int perB = pfx(64, cl);
    const int wblk = blockIdx.x;
    const int b    = wblk / perB;
    const int u    = wblk - b * perB;
    int lo = 0, hi = 63;
    while (lo < hi) {
        int mid = (lo + hi + 1) >> 1;
        if (pfx(mid, cl) <= u) lo = mid; else hi = mid - 1;
    }
    const int qt = lo;
    const int s  = u - pfx(qt, cl);
    const size_t sidx = (size_t)wblk;        // canonical partial slot

    const int T  = (qt + 2) >> 1;            // # 128-key tiles for this qt
    const int t0 = s << cl;
    int t1 = t0 + (1 << cl); if (t1 > T) t1 = T;

    const int wave = threadIdx.x >> 6;
    const int lane = threadIdx.x & 63;
    const int l16  = lane & 15;
    const int lg   = lane >> 4;

    __shared__ __align__(16) bf16 p_lds[4][16][128];   // 16 KB, XOR-swizzled
    char* pbase_lds = (char*)p_lds + wave * 4096;

    const int row0g = qt * 64 + wave * 16;

    const bf16* qbase = q + ((size_t)b * NN + row0g + l16) * DD + lg * 8;
    short8 qfrag0 = *(const short8*)(qbase);
    short8 qfrag1 = *(const short8*)(qbase + 32);

    f32x4 oacc[4];
    #pragma unroll
    for (int dt = 0; dt < 4; ++dt) oacc[dt] = (f32x4){0.f, 0.f, 0.f, 0.f};
    float m[4], l[4];
    #pragma unroll
    for (int r = 0; r < 4; ++r) { m[r] = -INFINITY; l[r] = 0.f; }

    const bf16* kbase0 = k + ((size_t)b * NN + l16) * DD + lg * 8;
    const bf16* vbase0 = vT + ((size_t)b * DD + l16) * NN + lg * 8;

    #pragma unroll 1
    for (int t = t0; t < t1; ++t) {
        const bf16* kbase = kbase0 + (size_t)t * 128 * DD;
        f32x4 sc[8];
        #pragma unroll
        for (int ct = 0; ct < 8; ++ct) sc[ct] = (f32x4){0.f, 0.f, 0.f, 0.f};

        {   // K in two half-batches (32 VGPRs at a time)
            short8 kf[4][2];
            #pragma unroll
            for (int ct = 0; ct < 4; ++ct) {
                kf[ct][0] = *(const short8*)(kbase + (size_t)ct * 16 * DD);
                kf[ct][1] = *(const short8*)(kbase + (size_t)ct * 16 * DD + 32);
            }
            #pragma unroll
            for (int ct = 0; ct < 4; ++ct) {
                mfma_16x16x32(sc[ct], qfrag0, kf[ct][0]);
                mfma_16x16x32(sc[ct], qfrag1, kf[ct][1]);
            }
            #pragma unroll
            for (int ct = 0; ct < 4; ++ct) {
                kf[ct][0] = *(const short8*)(kbase + (size_t)(ct + 4) * 16 * DD);
                kf[ct][1] = *(const short8*)(kbase + (size_t)(ct + 4) * 16 * DD + 32);
            }
            #pragma unroll
            for (int ct = 0; ct < 4; ++ct) {
                mfma_16x16x32(sc[ct + 4], qfrag0, kf[ct][0]);
                mfma_16x16x32(sc[ct + 4], qfrag1, kf[ct][1]);
            }
        }

        // early-issue V half A (kc 0..1) — latency hides under softmax
        const bf16* vbase = vbase0 + (size_t)t * 128;
        short8 vfA[4][2];
        #pragma unroll
        for (int dt = 0; dt < 4; ++dt) {
            vfA[dt][0] = *(const short8*)(vbase + (size_t)dt * 16 * NN);
            vfA[dt][1] = *(const short8*)(vbase + (size_t)dt * 16 * NN + 32);
        }

        // causal mask (only when tile touches the diagonal)
        if (t * 128 + 127 > row0g) {
            #pragma unroll
            for (int ct = 0; ct < 8; ++ct) {
                int gk = t * 128 + ct * 16 + l16;
                #pragma unroll
                for (int r = 0; r < 4; ++r)
                    if (gk > row0g + lg * 4 + r)
                        sc[ct][r] = -INFINITY;
            }
        }

        // online softmax over 128 keys
        float mt[4];
        #pragma unroll
        for (int r = 0; r < 4; ++r) {
            float a = fmaxf(fmaxf(sc[0][r], sc[1][r]), fmaxf(sc[2][r], sc[3][r]));
            float c = fmaxf(fmaxf(sc[4][r], sc[5][r]), fmaxf(sc[6][r], sc[7][r]));
            mt[r] = fmaxf(a, c);
        }
        #pragma unroll
        for (int off = 1; off < 16; off <<= 1)
            #pragma unroll
            for (int r = 0; r < 4; ++r)
                mt[r] = fmaxf(mt[r], __shfl_xor(mt[r], off));

        float alpha[4];
        #pragma unroll
        for (int r = 0; r < 4; ++r) {
            float mn = fmaxf(m[r], mt[r]);
            alpha[r] = __expf(m[r] - mn);
            m[r] = mn;
        }

        float ls[4] = {0.f, 0.f, 0.f, 0.f};
        #pragma unroll
        for (int ct = 0; ct < 8; ++ct)
            #pragma unroll
            for (int r = 0; r < 4; ++r) {
                float p = __expf(sc[ct][r] - m[r]);
                sc[ct][r] = p;
                ls[r] += p;
            }
        #pragma unroll
        for (int off = 1; off < 16; off <<= 1)
            #pragma unroll
            for (int r = 0; r < 4; ++r)
                ls[r] += __shfl_xor(ls[r], off);
        #pragma unroll
        for (int r = 0; r < 4; ++r)
            l[r] = l[r] * alpha[r] + ls[r];

        #pragma unroll
        for (int dt = 0; dt < 4; ++dt)
            #pragma unroll
            for (int r = 0; r < 4; ++r)
                oacc[dt][r] *= alpha[r];

        // P -> LDS (XOR-swizzled rows)
        #pragma unroll
        for (int ct = 0; ct < 8; ++ct)
            #pragma unroll
            for (int r = 0; r < 4; ++r) {
                int row_w = lg * 4 + r;
                int boff  = row_w * 256 + ((((ct * 16 + l16) * 2)) ^ ((row_w & 7) << 4));
                *(bf16*)(pbase_lds + boff) = __float2bfloat16(sc[ct][r]);
            }
        asm volatile("s_waitcnt lgkmcnt(0)" ::: "memory");

        // V half B (kc 2..3)
        short8 vfB[4][2];
        #pragma unroll
        for (int dt = 0; dt < 4; ++dt) {
            vfB[dt][0] = *(const short8*)(vbase + (size_t)dt * 16 * NN + 64);
            vfB[dt][1] = *(const short8*)(vbase + (size_t)dt * 16 * NN + 96);
        }

        short8 pa[4];
        #pragma unroll
        for (int kc = 0; kc < 4; ++kc)
            pa[kc] = *(const short8*)(pbase_lds + l16 * 256 +
                                      ((kc * 64 + lg * 16) ^ ((l16 & 7) << 4)));

        #pragma unroll
        for (int dt = 0; dt < 4; ++dt) {
            mfma_16x16x32(oacc[dt], pa[0], vfA[dt][0]);
            mfma_16x16x32(oacc[dt], pa[1], vfA[dt][1]);
            mfma_16x16x32(oacc[dt], pa[2], vfB[dt][0]);
            mfma_16x16x32(oacc[dt], pa[3], vfB[dt][1]);
        }
    }

    // write partials (unnormalized)
    #pragma unroll
    for (int r = 0; r < 4; ++r) {
        int row = wave * 16 + lg * 4 + r;
        #pragma unroll
        for (int dt = 0; dt < 4; ++dt)
            partO[sidx * 4096 + row * 64 + dt * 16 + l16] = oacc[dt][r];
        if (l16 == 0) {
            partML[sidx * 128 + row]      = m[r];
            partML[sidx * 128 + 64 + row] = l[r];
        }
    }
}

// ---------------- combine partials: 4 blocks per (b,qt) -------------------
__global__ __launch_bounds__(256) void combine_kernel(
    const float* __restrict__ partO, const float* __restrict__ partML,
    float* __restrict__ out, int cl)
{
    const int blk4 = blockIdx.x;             // (b*64+qt)*4 + quarter
    const int blk  = blk4 >> 2;
    const int qt   = blk & 63;
    const int b    = blk >> 6;
    const int tid  = threadIdx.x;
    const int row  = (blk4 & 3) * 16 + (tid >> 4);
    const int c    = (tid & 15) << 2;

    const int perB = pfx(64, cl);
    const size_t base = (size_t)b * perB + pfx(qt, cl);
    const int K2 = 2 << cl;
    const int U  = (qt + K2) >> (cl + 1);    // # work units for this qt

    float M = -INFINITY;
    for (int s = 0; s < U; ++s)
        M = fmaxf(M, partML[(base + s) * 128 + row]);

    float L = 0.f;
    f32x4 acc = (f32x4){0.f, 0.f, 0.f, 0.f};
    for (int s = 0; s < U; ++s) {
        float e = __expf(partML[(base + s) * 128 + row] - M);
        L += partML[(base + s) * 128 + 64 + row] * e;
        acc += *(const f32x4*)(partO + (base + s) * 4096 + row * 64 + c) * e;
    }
    *(f32x4*)(out + (size_t)blk * 4096 + row * 64 + c) = acc * (1.f / L);
}

extern "C" void kernel_launch(void* const* d_in, const int* in_sizes, int n_in,
                              void* d_out, int out_size, void* d_ws, size_t ws_size,
                              hipStream_t stream) {
    const float* x  = (const float*)d_in[0];
    const float* Wq = (const float*)d_in[1];
    const float* Wk = (const float*)d_in[2];
    const float* Wv = (const float*)d_in[3];

    bf16* q  = (bf16*)d_ws;
    bf16* k  = q  + (size_t)BB * NN * DD;
    bf16* vT = k  + (size_t)BB * NN * DD;
    bf16* WT = vT + (size_t)BB * NN * DD;
    char* pbase = (char*)(WT + 3 * DD * DIN);
    size_t mis = (size_t)pbase & 15;
    if (mis) pbase += 16 - mis;
    size_t fixed = (size_t)(pbase - (char*)d_ws);

    int cl = 1, perB = 0;
    for (; cl <= 3; ++cl) {
        perB = pfx(64, cl);
        size_t need = fixed + (size_t)BB * perB * (4096 + 128) * sizeof(float);
        if (need <= ws_size) break;
    }
    if (cl > 3) { cl = 3; perB = pfx(64, cl); }

    float* partO  = (float*)pbase;
    float* partML = partO + (size_t)BB * perB * 4096;

    convw_kernel<<<(3 * DD * DIN) / 256, 256, 0, stream>>>(Wq, Wk, Wv, WT);
    proj_kernel<<<BB * NN / 16, 256, 0, stream>>>(x, WT, q, k, vT);
    attn_split_kernel<<<BB * perB, 256, 0, stream>>>(q, k, vT, partO, partML, cl);
    combine_kernel<<<BB * 64 * 4, 256, 0, stream>>>(partO, partML, (float*)d_out, cl);
}

// Round 9
// 126.866 us; speedup vs baseline: 1.4550x; 1.0138x over previous
//
#include <hip/hip_runtime.h>
#include <hip/hip_bf16.h>

#define BB 4
#define NN 4096
#define DIN 512
#define DD 64

typedef __attribute__((ext_vector_type(8))) short short8;
typedef __attribute__((ext_vector_type(4))) float f32x4;
typedef __attribute__((ext_vector_type(4))) unsigned short us4;
typedef __attribute__((ext_vector_type(4))) unsigned int u32x4;
using bf16 = __hip_bfloat16;

__device__ inline void mfma_16x16x32(f32x4& d, short8 a, short8 b) {
    asm("v_mfma_f32_16x16x32_bf16 %0, %1, %2, %0" : "+v"(d) : "v"(a), "v"(b));
}

__device__ inline unsigned cvt_pk_bf16(float lo, float hi) {
    unsigned r;
    asm("v_cvt_pk_bf16_f32 %0, %1, %2" : "=v"(r) : "v"(lo), "v"(hi));
    return r;
}

__device__ inline short8 load_cvt8(const float* __restrict__ src) {
    f32x4 f0 = *(const f32x4*)(src);
    f32x4 f1 = *(const f32x4*)(src + 4);
    bf16 t[8];
    #pragma unroll
    for (int j = 0; j < 4; ++j) t[j]     = __float2bfloat16(f0[j]);
    #pragma unroll
    for (int j = 0; j < 4; ++j) t[4 + j] = __float2bfloat16(f1[j]);
    return *(short8*)t;
}

// prefix of work units: U(qt) = ceil(T(qt)/2^cl), T = (qt+2)>>1
__host__ __device__ inline int pfx(int qt, int cl) {
    int K = 2 << cl;                 // 2C
    int n = qt + K;
    int a = n >> (cl + 1);
    int r = n - (a << (cl + 1));
    return a * (a - 1) * (K >> 1) + r * a;
}

// ---------------- W transpose+convert: WT[g][kk] = W_{g/64}[kk][g%64] -----
__global__ __launch_bounds__(256) void convw_kernel(
    const float* __restrict__ Wq, const float* __restrict__ Wk,
    const float* __restrict__ Wv, bf16* __restrict__ WT)
{
    int idx = blockIdx.x * 256 + threadIdx.x;   // 3*64*512 = 98304
    int w   = idx >> 15;
    int rem = idx & 32767;
    int n   = rem >> 9;
    int kk  = rem & 511;
    const float* W = (w == 0) ? Wq : (w == 1) ? Wk : Wv;
    WT[idx] = __float2bfloat16(W[kk * DD + n]);
}

// ---------------- MFMA projection: 16 rows/block, 1024 blocks -------------
__global__ __launch_bounds__(256) void proj_kernel(
    const float* __restrict__ x, const bf16* __restrict__ WT,
    bf16* __restrict__ q, bf16* __restrict__ k, bf16* __restrict__ vT)
{
    const int tid   = threadIdx.x;
    const int row0  = blockIdx.x * 16;
    const int b     = row0 >> 12;
    const int nrow0 = row0 & 4095;
    const int lane  = tid & 63;
    const int l16   = lane & 15;
    const int lg    = lane >> 4;
    const int wave  = tid >> 6;
    const int cbase = wave * 48;

    f32x4 acc[3];
    #pragma unroll
    for (int ct = 0; ct < 3; ++ct) acc[ct] = (f32x4){0.f, 0.f, 0.f, 0.f};

    const float* xa = x  + (size_t)(row0 + l16) * DIN + lg * 8;
    const bf16*  wb = WT + (size_t)(cbase + l16) * DIN + lg * 8;

    #pragma unroll 4
    for (int ks = 0; ks < 16; ++ks) {
        short8 a  = load_cvt8(xa + ks * 32);
        short8 w0 = *(const short8*)(wb + ks * 32);
        short8 w1 = *(const short8*)(wb + 16 * DIN + ks * 32);
        short8 w2 = *(const short8*)(wb + 32 * DIN + ks * 32);
        mfma_16x16x32(acc[0], a, w0);
        mfma_16x16x32(acc[1], a, w1);
        mfma_16x16x32(acc[2], a, w2);
    }

    #pragma unroll
    for (int ct = 0; ct < 3; ++ct) {
        int g = cbase + ct * 16 + l16;
        int w = g >> 6;
        int n = g & 63;
        if (w == 2) {
            us4 pv;
            #pragma unroll
            for (int r = 0; r < 4; ++r) {
                bf16 hv = __float2bfloat16(acc[ct][r]);
                pv[r] = *(unsigned short*)&hv;
            }
            *(us4*)(vT + ((size_t)b * DD + n) * NN + nrow0 + lg * 4) = pv;
        } else {
            bf16* dst = (w == 0) ? q : k;
            float sc  = (w == 0) ? 0.125f : 1.0f;
            #pragma unroll
            for (int r = 0; r < 4; ++r) {
                int row = nrow0 + lg * 4 + r;
                dst[((size_t)b * NN + row) * DD + n] =
                    __float2bfloat16(acc[ct][r] * sc);
            }
        }
    }
}

// ---------------- equal-work split-KV flash attention ---------------------
// swapped-QK layout: lane holds P[qrow = l16][keys ct*16 + lg*4 + r]
__global__ __launch_bounds__(256) void attn_split_kernel(
    const bf16* __restrict__ q, const bf16* __restrict__ k,
    const bf16* __restrict__ vT,
    float* __restrict__ partO, float* __restrict__ partML, int cl)
{
    const int perB = pfx(64, cl);
    const int wblk = blockIdx.x;
    const int b    = wblk / perB;
    const int u    = wblk - b * perB;
    int lo = 0, hi = 63;
    while (lo < hi) {
        int mid = (lo + hi + 1) >> 1;
        if (pfx(mid, cl) <= u) lo = mid; else hi = mid - 1;
    }
    const int qt = lo;
    const int s  = u - pfx(qt, cl);
    const size_t sidx = (size_t)wblk;        // canonical partial slot

    const int T  = (qt + 2) >> 1;            // # 128-key tiles for this qt
    const int t0 = s << cl;
    int t1 = t0 + (1 << cl); if (t1 > T) t1 = T;

    const int wave = threadIdx.x >> 6;
    const int lane = threadIdx.x & 63;
    const int l16  = lane & 15;
    const int lg   = lane >> 4;

    const int row0g = qt * 64 + wave * 16;
    const int qrow  = row0g + l16;           // this lane's softmax row

    const bf16* qbase = q + ((size_t)b * NN + row0g + l16) * DD + lg * 8;
    short8 qfrag0 = *(const short8*)(qbase);
    short8 qfrag1 = *(const short8*)(qbase + 32);

    f32x4 oacc[4];
    #pragma unroll
    for (int dt = 0; dt < 4; ++dt) oacc[dt] = (f32x4){0.f, 0.f, 0.f, 0.f};
    float m = -INFINITY, l = 0.f;

    const bf16* kbase0 = k + ((size_t)b * NN + l16) * DD + lg * 8;
    const bf16* vbase0 = vT + ((size_t)b * DD + l16) * NN + lg * 8;

    #pragma unroll 1
    for (int t = t0; t < t1; ++t) {
        const bf16* kbase = kbase0 + (size_t)t * 128 * DD;
        f32x4 sc[8];
        #pragma unroll
        for (int ct = 0; ct < 8; ++ct) sc[ct] = (f32x4){0.f, 0.f, 0.f, 0.f};

        {   // K in two half-batches; SWAPPED operand order: A=K, B=Q
            short8 kf[4][2];
            #pragma unroll
            for (int ct = 0; ct < 4; ++ct) {
                kf[ct][0] = *(const short8*)(kbase + (size_t)ct * 16 * DD);
                kf[ct][1] = *(const short8*)(kbase + (size_t)ct * 16 * DD + 32);
            }
            __builtin_amdgcn_s_setprio(1);
            #pragma unroll
            for (int ct = 0; ct < 4; ++ct) {
                mfma_16x16x32(sc[ct], kf[ct][0], qfrag0);
                mfma_16x16x32(sc[ct], kf[ct][1], qfrag1);
            }
            __builtin_amdgcn_s_setprio(0);
            #pragma unroll
            for (int ct = 0; ct < 4; ++ct) {
                kf[ct][0] = *(const short8*)(kbase + (size_t)(ct + 4) * 16 * DD);
                kf[ct][1] = *(const short8*)(kbase + (size_t)(ct + 4) * 16 * DD + 32);
            }
            __builtin_amdgcn_s_setprio(1);
            #pragma unroll
            for (int ct = 0; ct < 4; ++ct) {
                mfma_16x16x32(sc[ct + 4], kf[ct][0], qfrag0);
                mfma_16x16x32(sc[ct + 4], kf[ct][1], qfrag1);
            }
            __builtin_amdgcn_s_setprio(0);
        }

        // early-issue V half A (keys 0..63 of tile)
        const bf16* vbase = vbase0 + (size_t)t * 128;
        short8 vfA[4][2];
        #pragma unroll
        for (int dt = 0; dt < 4; ++dt) {
            vfA[dt][0] = *(const short8*)(vbase + (size_t)dt * 16 * NN);
            vfA[dt][1] = *(const short8*)(vbase + (size_t)dt * 16 * NN + 32);
        }

        // causal mask: key = t*128 + ct*16 + lg*4 + r vs qrow
        if (t * 128 + 127 > row0g) {
            #pragma unroll
            for (int ct = 0; ct < 8; ++ct) {
                int gk = t * 128 + ct * 16 + lg * 4;
                #pragma unroll
                for (int r = 0; r < 4; ++r)
                    if (gk + r > qrow)
                        sc[ct][r] = -INFINITY;
            }
        }

        // ---- in-register softmax (one q-row per lane) ----
        float m4[8];
        #pragma unroll
        for (int ct = 0; ct < 8; ++ct)
            m4[ct] = fmaxf(fmaxf(sc[ct][0], sc[ct][1]), fmaxf(sc[ct][2], sc[ct][3]));
        float mt = fmaxf(fmaxf(fmaxf(m4[0], m4[1]), fmaxf(m4[2], m4[3])),
                         fmaxf(fmaxf(m4[4], m4[5]), fmaxf(m4[6], m4[7])));
        mt = fmaxf(mt, __shfl_xor(mt, 16));
        mt = fmaxf(mt, __shfl_xor(mt, 32));

        float mn    = fmaxf(m, mt);
        float alpha = __expf(m - mn);
        m = mn;

        float s4[8];
        #pragma unroll
        for (int ct = 0; ct < 8; ++ct) {
            float p0 = __expf(sc[ct][0] - m);
            float p1 = __expf(sc[ct][1] - m);
            float p2 = __expf(sc[ct][2] - m);
            float p3 = __expf(sc[ct][3] - m);
            sc[ct][0] = p0; sc[ct][1] = p1; sc[ct][2] = p2; sc[ct][3] = p3;
            s4[ct] = (p0 + p1) + (p2 + p3);
        }
        float ls = ((s4[0] + s4[1]) + (s4[2] + s4[3])) +
                   ((s4[4] + s4[5]) + (s4[6] + s4[7]));
        ls += __shfl_xor(ls, 16);
        ls += __shfl_xor(ls, 32);
        l = l * alpha + ls;

        // alpha redistribution to D-layout rows (lg*4+r) + O rescale
        float ar[4];
        #pragma unroll
        for (int r = 0; r < 4; ++r) ar[r] = __shfl(alpha, lg * 4 + r);
        #pragma unroll
        for (int dt = 0; dt < 4; ++dt)
            #pragma unroll
            for (int r = 0; r < 4; ++r)
                oacc[dt][r] *= ar[r];

        // P -> bf16 pairs in registers: hw[ct*2+w] = pack(sc[ct][2w], sc[ct][2w+1])
        unsigned hw[16];
        #pragma unroll
        for (int ct = 0; ct < 8; ++ct) {
            hw[ct * 2]     = cvt_pk_bf16(sc[ct][0], sc[ct][1]);
            hw[ct * 2 + 1] = cvt_pk_bf16(sc[ct][2], sc[ct][3]);
        }

        // V half B (keys 64..127)
        short8 vfB[4][2];
        #pragma unroll
        for (int dt = 0; dt < 4; ++dt) {
            vfB[dt][0] = *(const short8*)(vbase + (size_t)dt * 16 * NN + 64);
            vfB[dt][1] = *(const short8*)(vbase + (size_t)dt * 16 * NN + 96);
        }

        // ---- register P redistribution to A-fragment layout ----
        // pa[kc] word v <- lane(l16 + (lg&1)*32 + (v>>1)*16), hw[(kc*2+(lg>>1))*2 + (v&1)]
        const int srcA = (lane & 15) | ((lane & 16) << 1);
        const int srcB = srcA + 16;
        const bool hi2 = (lane & 32) != 0;   // lg>>1
        short8 pa[4];
        #pragma unroll
        for (int kc = 0; kc < 4; ++kc) {
            unsigned a0 = (unsigned)__shfl((int)hw[4 * kc + 0], srcA);
            unsigned a1 = (unsigned)__shfl((int)hw[4 * kc + 1], srcA);
            unsigned a2 = (unsigned)__shfl((int)hw[4 * kc + 0], srcB);
            unsigned a3 = (unsigned)__shfl((int)hw[4 * kc + 1], srcB);
            unsigned b0 = (unsigned)__shfl((int)hw[4 * kc + 2], srcA);
            unsigned b1 = (unsigned)__shfl((int)hw[4 * kc + 3], srcA);
            unsigned b2 = (unsigned)__shfl((int)hw[4 * kc + 2], srcB);
            unsigned b3 = (unsigned)__shfl((int)hw[4 * kc + 3], srcB);
            u32x4 wv = hi2 ? (u32x4){b0, b1, b2, b3} : (u32x4){a0, a1, a2, a3};
            pa[kc] = __builtin_bit_cast(short8, wv);
        }

        // ---- O += P V ----
        __builtin_amdgcn_s_setprio(1);
        #pragma unroll
        for (int dt = 0; dt < 4; ++dt) {
            mfma_16x16x32(oacc[dt], pa[0], vfA[dt][0]);
            mfma_16x16x32(oacc[dt], pa[1], vfA[dt][1]);
            mfma_16x16x32(oacc[dt], pa[2], vfB[dt][0]);
            mfma_16x16x32(oacc[dt], pa[3], vfB[dt][1]);
        }
        __builtin_amdgcn_s_setprio(0);
    }

    // write partials (unnormalized)
    #pragma unroll
    for (int r = 0; r < 4; ++r) {
        int row = wave * 16 + lg * 4 + r;
        #pragma unroll
        for (int dt = 0; dt < 4; ++dt)
            partO[sidx * 4096 + row * 64 + dt * 16 + l16] = oacc[dt][r];
    }
    if (lg == 0) {
        partML[sidx * 128 + wave * 16 + l16]      = m;
        partML[sidx * 128 + 64 + wave * 16 + l16] = l;
    }
}

// ---------------- combine partials: 4 blocks per (b,qt) -------------------
__global__ __launch_bounds__(256) void combine_kernel(
    const float* __restrict__ partO, const float* __restrict__ partML,
    float* __restrict__ out, int cl)
{
    const int blk4 = blockIdx.x;             // (b*64+qt)*4 + quarter
    const int blk  = blk4 >> 2;
    const int qt   = blk & 63;
    const int b    = blk >> 6;
    const int tid  = threadIdx.x;
    const int row  = (blk4 & 3) * 16 + (tid >> 4);
    const int c    = (tid & 15) << 2;

    const int perB = pfx(64, cl);
    const size_t base = (size_t)b * perB + pfx(qt, cl);
    const int K2 = 2 << cl;
    const int U  = (qt + K2) >> (cl + 1);    // # work units for this qt

    float M = -INFINITY;
    for (int s = 0; s < U; ++s)
        M = fmaxf(M, partML[(base + s) * 128 + row]);

    float L = 0.f;
    f32x4 acc = (f32x4){0.f, 0.f, 0.f, 0.f};
    for (int s = 0; s < U; ++s) {
        float e = __expf(partML[(base + s) * 128 + row] - M);
        L += partML[(base + s) * 128 + 64 + row] * e;
        acc += *(const f32x4*)(partO + (base + s) * 4096 + row * 64 + c) * e;
    }
    *(f32x4*)(out + (size_t)blk * 4096 + row * 64 + c) = acc * (1.f / L);
}

extern "C" void kernel_launch(void* const* d_in, const int* in_sizes, int n_in,
                              void* d_out, int out_size, void* d_ws, size_t ws_size,
                              hipStream_t stream) {
    const float* x  = (const float*)d_in[0];
    const float* Wq = (const float*)d_in[1];
    const float* Wk = (const float*)d_in[2];
    const float* Wv = (const float*)d_in[3];

    bf16* q  = (bf16*)d_ws;
    bf16* k  = q  + (size_t)BB * NN * DD;
    bf16* vT = k  + (size_t)BB * NN * DD;
    bf16* WT = vT + (size_t)BB * NN * DD;
    char* pbase = (char*)(WT + 3 * DD * DIN);
    size_t mis = (size_t)pbase & 15;
    if (mis) pbase += 16 - mis;
    size_t fixed = (size_t)(pbase - (char*)d_ws);

    int cl = 1, perB = 0;
    for (; cl <= 3; ++cl) {
        perB = pfx(64, cl);
        size_t need = fixed + (size_t)BB * perB * (4096 + 128) * sizeof(float);
        if (need <= ws_size) break;
    }
    if (cl > 3) { cl = 3; perB = pfx(64, cl); }

    float* partO  = (float*)pbase;
    float* partML = partO + (size_t)BB * perB * 4096;

    convw_kernel<<<(3 * DD * DIN) / 256, 256, 0, stream>>>(Wq, Wk, Wv, WT);
    proj_kernel<<<BB * NN / 16, 256, 0, stream>>>(x, WT, q, k, vT);
    attn_split_kernel<<<BB * perB, 256, 0, stream>>>(q, k, vT, partO, partML, cl);
    combine_kernel<<<BB * 64 * 4, 256, 0, stream>>>(partO, partML, (float*)d_out, cl);
}